// Round 6
// baseline (262.456 us; speedup 1.0000x reference)
//
#include <hip/hip_runtime.h>

// Spatial transformer: affine grid-sample, reflect padding, bilinear.
// x: (B=32, C=3, H=512, W=512) fp32; p: (B,4) fp32 = [tx, ty, theta, scale].
//
// R9: R8 (53us) still 1.8x above the 30us mixed-stream floor with VALU, LDS,
// HBM all underutilized -> residual = 5 per-block barrier drains (each forces
// vmcnt(0)+lgkmcnt(0) for all waves). This round removes ALL barriers:
//  - wave-private staging: each wave owns a 16x16 output patch (block = 32x32
//    tile x 3ch = 2x2 patches x 4 waves). Footprint half-extent 7.5(|a|+|bb|)
//    <= 10.6 -> worst-case box 34 wide x 31 rows fits 32 rows x 40 words =
//    5120B/wave, 20480B/block -> exactly 8 blocks/CU. Zero __syncthreads.
//  - DS ops are in-order per wave: ds_writes of ch(k+1) cannot pass ds_reads
//    of ch(k), so single-buffer reuse is race-free without sync.
//  - ch(k+1) global loads issued before ch(k) gather: HBM latency hides under
//    gather+store, gated by per-wave vmcnt only (no block-wide drain).
//  - geometry (idx4/fx/fy) computed once, reused for 3 channels (R8).
//  - zero pad column at slot nw4 + zero guard row at nrows: zero-weight x1/y1
//    taps always read finite LDS (R5-R8 proven logic).

#define B_ 32
#define C_ 3
#define H_ 512
#define W_ 512
#define TILE 32
#define PTILE 16
#define LSTRIDE 40                     // 10 float4 slots; max 9 data + 1 pad
#define WROWS 32                       // max 31 data rows + 1 guard row
#define WWORDS (WROWS * LSTRIDE)       // 1280 words = 5120 B per wave

typedef float f32x4 __attribute__((ext_vector_type(4)));

// reflect onto [0, 511], half-pixel convention; exact for pow2 size (bit-
// identical to the reference's floor/fmod/parity form).
__device__ __forceinline__ float reflect512(float coord) {
    const float c = fabsf(coord + 0.5f);
    const float m = c - floorf(c * (1.0f / 1024.0f)) * 1024.0f;   // c mod 1024
    const float t = 512.0f - fabsf(m - 512.0f);
    return fminf(fmaxf(t - 0.5f, 0.0f), 511.0f);
}

__global__ __launch_bounds__(256, 8)
void st_kernel(const float* __restrict__ x, const float* __restrict__ p,
               float* __restrict__ out) {
    __shared__ float smem[4 * WWORDS];  // 20,480 B -> 8 blocks/CU exactly

    const int tid  = threadIdx.x;
    const int wv   = tid >> 6;          // wave 0..3 -> 2x2 patch grid
    const int lane = tid & 63;

    // ---- XCD-chunked work swizzle (grid 8192 = 8 * 1024, bijective) ----
    const int bid = blockIdx.x;
    const int wid = (bid & 7) * 1024 + (bid >> 3);
    const int b   = wid >> 8;           // 0..31
    const int til = wid & 255;
    const int tlx = til & 15;
    const int tly = til >> 4;

    const float tx = p[b * 4 + 0];
    const float ty = p[b * 4 + 1];
    const float th = p[b * 4 + 2];
    const float ts = p[b * 4 + 3];
    const float cth = __cosf(th), sth = __sinf(th);
    const float a  =  ts * cth;         // ix step per output col
    const float bb = -ts * sth;         // ix step per output row
    const float d  =  ts * sth;         // iy step per output col (e == a)

    // ---- wave-private 16x16 patch ----
    const int porow = tly * TILE + (wv >> 1) * PTILE;
    const int pocol = tlx * TILE + (wv & 1) * PTILE;

    // patch center (pixel centers span +0.5..+15.5 -> midpoint +8)
    const float xs_c = ((float)pocol + 8.0f) * (2.0f / W_) - 1.0f;
    const float ys_c = ((float)porow + 8.0f) * (2.0f / H_) - 1.0f;
    const float gxc = a * xs_c + bb * ys_c + tx;
    const float gyc = d * xs_c + a  * ys_c + ty;
    const float rcx = reflect512(((gxc + 1.0f) * W_ - 1.0f) * 0.5f);
    const float rcy = reflect512(((gyc + 1.0f) * H_ - 1.0f) * 0.5f);
    // per-px |delta| <= 7.5(|a|+|bb|); reflect+clip 1-Lipschitz; +3 slack.
    const float ext = 8.0f * (fabsf(a) + fabsf(bb)) + 3.0f;     // <= 14.32

    int bx0 = max((int)floorf(rcx - ext), 0) & ~3;              // 16B-aligned
    const int xhi = min((int)ceilf(rcx + ext) + 1, W_);         // +1: real x1 tap
    int nw4 = (xhi - bx0 + 3) >> 2;
    nw4 = min(min(nw4, 9), (W_ - bx0) >> 2);                    // <= 9 data slots

    int by0 = max((int)floorf(rcy - ext), 0);
    const int yhi = min((int)ceilf(rcy + ext) + 1, H_);
    const int nrows = min(yhi - by0, WROWS - 1);                // <= 31 data rows

    const size_t plane = (size_t)H_ * W_;
    const float* img = x + (size_t)b * C_ * plane;
    const size_t goff = (size_t)by0 * W_ + bx0;

    float* wbase = &smem[wv * WWORDS];
    const int slot = lane & 15;         // float4 slot (0..9 used)
    const int r0   = lane >> 4;         // 0..3; rows r0+4i, i=0..7 cover 32
    const int ccl  = min(slot, max(nw4 - 1, 0)) * 4;  // clamped load column

    f32x4 vr[8];
    auto load_ch = [&](int ch) {        // unconditional clamped loads: 1 vmcnt group
        const float* gp = img + (size_t)ch * plane + goff;
        #pragma unroll
        for (int i = 0; i < 8; ++i) {
            const int rr = min(r0 + 4 * i, nrows - 1);
            vr[i] = *reinterpret_cast<const f32x4*>(gp + (size_t)rr * W_ + ccl);
        }
    };
    auto write_ch = [&]() {             // predicated ds_writes
        #pragma unroll
        for (int i = 0; i < 8; ++i) {
            const int r = r0 + 4 * i;
            if (r < nrows && slot < nw4)
                *reinterpret_cast<f32x4*>(wbase + r * LSTRIDE + slot * 4) = vr[i];
        }
    };

    load_ch(0);                         // ch0 in flight

    // ---- per-px state, once for all 3 channels (overlaps ch0 latency) ----
    const int lrow = lane >> 2;         // 0..15
    const int lcol = (lane & 3) * 4;    // 0,4,8,12
    const int row  = porow + lrow;
    const int col0 = pocol + lcol;

    const float ysn = ((float)row  + 0.5f) * (2.0f / H_) - 1.0f;
    const float xsn = ((float)col0 + 0.5f) * (2.0f / W_) - 1.0f;
    float ix = ((a * xsn + bb * ysn + tx + 1.0f) * W_ - 1.0f) * 0.5f;
    float iy = ((d * xsn + a  * ysn + ty + 1.0f) * H_ - 1.0f) * 0.5f;

    const int koff = by0 * LSTRIDE + bx0;
    int   idx4[4];
    float fx_[4], fy_[4];
    #pragma unroll
    for (int k = 0; k < 4; ++k) {
        const float rx  = reflect512(ix);
        const float ry  = reflect512(iy);
        const float x0f = floorf(rx);
        const float y0f = floorf(ry);
        fx_[k] = rx - x0f;
        fy_[k] = ry - y0f;
        idx4[k] = (int)y0f * LSTRIDE + (int)x0f - koff;
        ix += a;
        iy += d;
    }

    // ---- pads, written once (persist across channels) ----
    if (slot == nw4) {                  // zero column after staged width
        #pragma unroll
        for (int i = 0; i < 8; ++i) {
            const int r = r0 + 4 * i;
            if (r < nrows)
                *reinterpret_cast<f32x4*>(wbase + r * LSTRIDE + slot * 4) = (f32x4)(0.0f);
        }
    }
    if (lane < 10)                      // zero guard row (y1 taps at row nrows)
        *reinterpret_cast<f32x4*>(wbase + nrows * LSTRIDE + lane * 4) = (f32x4)(0.0f);

    write_ch();                         // ch0 -> LDS (per-wave vmcnt wait only)

    float* outp = out + (size_t)b * C_ * plane + (size_t)row * W_ + col0;

    #pragma unroll
    for (int ch = 0; ch < C_; ++ch) {
        if (ch < C_ - 1)
            load_ch(ch + 1);            // next channel's HBM latency hides under
                                        // this channel's gather+store
        float acc[4];
        #pragma unroll
        for (int k = 0; k < 4; ++k) {   // compiler waits lgkmcnt for ds data
            const float fx = fx_[k], fy = fy_[k];
            const float ox = 1.0f - fx, oy = 1.0f - fy;
            const float* s = wbase + idx4[k];
            acc[k] = s[0] * (ox * oy) + s[1] * (fx * oy)
                   + s[LSTRIDE] * (ox * fy) + s[LSTRIDE + 1] * (fx * fy);
        }
        const f32x4 v = {acc[0], acc[1], acc[2], acc[3]};
        *reinterpret_cast<f32x4*>(outp + (size_t)ch * plane) = v;

        if (ch < C_ - 1)
            write_ch();                 // DS pipe is in-order per wave: these
                                        // writes cannot pass the reads above
    }
}

extern "C" void kernel_launch(void* const* d_in, const int* in_sizes, int n_in,
                              void* d_out, int out_size, void* d_ws, size_t ws_size,
                              hipStream_t stream) {
    const float* x = (const float*)d_in[0];
    const float* p = (const float*)d_in[1];
    float* out = (float*)d_out;

    dim3 block(256, 1, 1);
    dim3 grid((W_ / TILE) * (H_ / TILE) * B_, 1, 1);    // 8192
    st_kernel<<<grid, block, 0, stream>>>(x, p, out);
}